// Round 5
// baseline (89.228 us; speedup 1.0000x reference)
//
#include <hip/hip_runtime.h>
#include <math.h>

#define BB 8
#define HH 256
#define WW 256
#define NPIX (BB*HH*WW)   // 524288
#define BIGI 512          // H + W, the reference cap
#define BIGBIG (1<<20)
#define MAGIC 0x9E3779B97F4A7C15ull

// ws layout (u32 units):
//  MASK_OFF : u32 masks[8 img][8 word][256 col]  = 16384 u32 (64 KB)
//  SFLAG_OFF: 64 slab flags, u64 each, stride 4 u32 (16 B)
//  SLOT_OFF : 512 block slots x 4 u32 {partial(float), pad, flag_lo, flag_hi}
// No init needed: harness re-poisons ws each iteration (repeated-dword fill
// can never equal the 64-bit MAGIC whose halves differ); all cross-block
// data is gated by release/acquire MAGIC flags (pattern verified round 4).
#define MASK_OFF  0
#define SFLAG_OFF 16384
#define SLOT_OFF  17408

#define ENV_GROUP(kk) { float4 v = s4[kk];                        \
    float D0 = fw - (float)(4 * (kk));                            \
    d2 = fminf(d2, fmaf(D0, D0, v.x));                            \
    float D1 = D0 - 1.0f; d2 = fminf(d2, fmaf(D1, D1, v.y));      \
    float D2 = D0 - 2.0f; d2 = fminf(d2, fmaf(D2, D2, v.z));      \
    float D3 = D0 - 3.0f; d2 = fminf(d2, fmaf(D3, D3, v.w)); }

// ---------------------------------------------------------------------------
// Single launch, producer-consumer inside one kernel, ZERO redundant work.
// Blocks 0..63: pack slab (im=bid>>3, word j=bid&7): 8 coalesced row-loads
//   per thread (quarter-word), LDS merge, publish 1 KB of masks + release
//   MAGIC slab flag. Producers never wait first => deadlock-free.
// All 512 blocks: acquire-poll the 8 slab flags of their image, then the
//   round-3-verified math: clz/ctz vertical distances from masks, center-out
//   lower envelope (+-64 window), loss, block reduce, slot+flag store;
//   block 0 polls 512 slot flags and writes out[0] (round-4-verified).
// ---------------------------------------------------------------------------
__global__ __launch_bounds__(1024, 8) void fused_boundary_pc(
    const float* __restrict__ pred,
    const float* __restrict__ tgt,
    float* __restrict__ ws,
    float* __restrict__ out) {
  // lA = lbuf[0..1023] rows r*256 ; lB = lbuf+1028 (16-B pad => disjoint
  // banks for the fg-divergent b128 reads). Packers reuse lbuf as u32 scratch.
  __shared__ __align__(16) float lbuf[2 * 4 * WW + 4];
  __shared__ float wsum[16];

  unsigned int* wsu = (unsigned int*)ws;
  unsigned int* maskws = wsu + MASK_OFF;

  int tid = threadIdx.x;
  int bid = blockIdx.x;
  int im = bid >> 6;          // consumer image
  int rg = bid & 63;          // consumer row-group (4 rows)

  float x = pred[(size_t)bid * 1024 + tid];   // issue early

  // ---- producer phase: blocks 0..63 pack one (image, word-slab) ----
  if (bid < 64) {
    int pim = bid >> 3;       // packed image
    int pj = bid & 7;         // word (rows 32pj..32pj+31)
    int c = tid & 255;        // column
    int q = tid >> 8;         // quarter (rows 8q..8q+7 of the word)
    size_t pb = (size_t)pim * (HH * WW) + (size_t)(32 * pj + 8 * q) * WW + c;
    unsigned int mq = 0;
#pragma unroll
    for (int i = 0; i < 8; ++i) {
      float t = tgt[pb + (size_t)i * WW];
      mq |= (t > 0.5f ? 1u : 0u) << i;
    }
    unsigned int* pack_lds = (unsigned int*)lbuf;
    pack_lds[q * 256 + c] = mq;   // 8-bit chunk
    __syncthreads();
    if (q == 0) {
      unsigned int m = pack_lds[c] | (pack_lds[256 + c] << 8) |
                       (pack_lds[512 + c] << 16) | (pack_lds[768 + c] << 24);
      maskws[pim * 2048 + pj * 256 + c] = m;
    }
    __syncthreads();
    if (tid == 0) {
      __threadfence();
      __hip_atomic_store(
          (unsigned long long*)(wsu + SFLAG_OFF + (pim * 8 + pj) * 4), MAGIC,
          __ATOMIC_RELEASE, __HIP_MEMORY_SCOPE_AGENT);
    }
    __syncthreads();  // lbuf free for consumer reuse
  }

  // ---- consumer phase: wait for this image's 8 slabs ----
  if (tid < 8) {
    unsigned long long* fp =
        (unsigned long long*)(wsu + SFLAG_OFF + (im * 8 + tid) * 4);
    while (__hip_atomic_load(fp, __ATOMIC_ACQUIRE,
                             __HIP_MEMORY_SCOPE_AGENT) != MAGIC)
      __builtin_amdgcn_s_sleep(2);
  }
  __syncthreads();

  int r = tid >> 8;           // row within group (wave-uniform)
  int w = tid & 255;          // column
  int R = 4 * rg + r;         // row in image
  int k = R >> 5;             // word id (wave-uniform)
  int rr = R & 31;            // bit within word

  unsigned int M[8];
#pragma unroll
  for (int j = 0; j < 8; ++j) M[j] = maskws[im * 2048 + j * 256 + w];

  // cross-word carries (A = bg = ~fg, B = fg) — verified chains
  int fcA = BIGBIG, fcB = BIGBIG, bcA = BIGBIG, bcB = BIGBIG;
  {
    int cA = BIGBIG, cB = BIGBIG;
#pragma unroll
    for (int j = 0; j < 8; ++j) {
      if (j == k) { fcA = cA; fcB = cB; }
      unsigned int a = ~M[j], bm = M[j];
      cA = a  ? (int)__builtin_clz(a)  : cA + 32;
      cB = bm ? (int)__builtin_clz(bm) : cB + 32;
    }
  }
  {
    int cA = BIGBIG, cB = BIGBIG;
#pragma unroll
    for (int j = 7; j >= 0; --j) {
      if (j == k) { bcA = cA; bcB = cB; }
      unsigned int a = ~M[j], bm = M[j];
      cA = a  ? (int)__builtin_ctz(a)  : cA + 32;
      cB = bm ? (int)__builtin_ctz(bm) : cB + 32;
    }
  }

  unsigned int mk = M[k];
  bool fg = (mk >> rr) & 1u;
  float t = fg ? 1.0f : 0.0f;

  float* lA = lbuf + r * WW;
  float* lB = lbuf + 1028 + r * WW;
  {
    unsigned int mA = ~mk;
    unsigned int xx = mA << (31 - rr);
    unsigned int yy = mA >> rr;
    int df = xx ? (int)__builtin_clz(xx) : (rr + 1 + fcA);
    int db = yy ? (int)__builtin_ctz(yy) : (32 - rr + bcA);
    int d = min(min(df, db), BIGI);
    lA[w] = (float)(d * d);
  }
  {
    unsigned int xx = mk << (31 - rr);
    unsigned int yy = mk >> rr;
    int df = xx ? (int)__builtin_clz(xx) : (rr + 1 + fcB);
    int db = yy ? (int)__builtin_ctz(yy) : (32 - rr + bcB);
    int d = min(min(df, db), BIGI);
    lB[w] = (float)(d * d);
  }
  __syncthreads();

  // center-out lower envelope + loss (unchanged, verified)
  const float4* s4 = (const float4*)(fg ? lA : lB);

  int w0 = w & ~63;
  int kc0 = w0 >> 2;
  float fw = (float)w;
  float d2 = 1e30f;

#pragma unroll 4
  for (int kk = kc0; kk < kc0 + 16; ++kk) ENV_GROUP(kk);

  int kL = kc0 - 1;
  int kR = kc0 + 16;
  for (int iter = 0; iter < 16; ++iter) {
    int bL = (kL >= 0) ? (w0 - 4 * kL - 3) : 100000;
    int bR = (kR <= 63) ? (4 * kR - w0 - 63) : 100000;
    int bb = min(bL, bR);
    float bb2 = (float)bb * (float)bb;
    if (__all(d2 <= bb2)) break;
    if (kL >= 0) { ENV_GROUP(kL); kL--; }
    if (kR <= 63) { ENV_GROUP(kR); kR++; }
  }

  float dd = sqrtf(d2);
  float weight = 1.0f / (1.0f + __expf((dd - 3.0f) * 0.2f));
  float bce = fmaxf(x, 0.0f) - x * t + log1pf(__expf(-fabsf(x)));
  float c = bce * weight * (1.0f / (float)NPIX);

  // block reduce -> slot store + flag (round-4-verified, no init needed)
#pragma unroll
  for (int off = 32; off > 0; off >>= 1) c += __shfl_down(c, off, 64);
  if ((tid & 63) == 0) wsum[tid >> 6] = c;
  __syncthreads();

  if (tid < 64) {
    float v = (tid < 16) ? wsum[tid] : 0.0f;
#pragma unroll
    for (int off = 8; off > 0; off >>= 1) v += __shfl_down(v, off, 64);
    if (tid == 0) {
      float* slot = (float*)(wsu + SLOT_OFF + (size_t)bid * 4);
      slot[0] = v;
      __threadfence();
      __hip_atomic_store((unsigned long long*)(slot + 2), MAGIC,
                         __ATOMIC_RELEASE, __HIP_MEMORY_SCOPE_AGENT);
    }
  }

  // block 0: poll all 512 slot flags, final reduce, write out
  if (bid == 0) {
    __syncthreads();
    float v = 0.0f;
    if (tid < 512) {
      unsigned long long* fp =
          (unsigned long long*)(wsu + SLOT_OFF + (size_t)tid * 4 + 2);
      while (__hip_atomic_load(fp, __ATOMIC_ACQUIRE,
                               __HIP_MEMORY_SCOPE_AGENT) != MAGIC)
        __builtin_amdgcn_s_sleep(8);
      v = ((float*)(wsu + SLOT_OFF))[(size_t)tid * 4];
    }
#pragma unroll
    for (int off = 32; off > 0; off >>= 1) v += __shfl_down(v, off, 64);
    if ((tid & 63) == 0) wsum[tid >> 6] = v;
    __syncthreads();
    if (tid < 64) {
      float s = (tid < 16) ? wsum[tid] : 0.0f;
#pragma unroll
      for (int off = 8; off > 0; off >>= 1) s += __shfl_down(s, off, 64);
      if (tid == 0) out[0] = s;
    }
  }
}

extern "C" void kernel_launch(void* const* d_in, const int* in_sizes, int n_in,
                              void* d_out, int out_size, void* d_ws, size_t ws_size,
                              hipStream_t stream) {
  const float* pred = (const float*)d_in[0];
  const float* tgt  = (const float*)d_in[1];
  float* out = (float*)d_out;
  float* ws  = (float*)d_ws;

  fused_boundary_pc<<<dim3(512), dim3(1024), 0, stream>>>(pred, tgt, ws, out);
}

// Round 6
// 69.903 us; speedup vs baseline: 1.2765x; 1.2765x over previous
//
#include <hip/hip_runtime.h>
#include <math.h>

#define BB 8
#define HH 256
#define WW 256
#define NPIX (BB*HH*WW)   // 524288
#define BIGI 512          // H + W, the reference cap
#define BIGBIG (1<<20)

// ws layout: masks (u32) [0, 16384) = 64 KB, TRANSPOSED: mask[im][w][j]
//            (im=0..7 image, w=0..255 column, j=0..7 word of rows 32j..32j+31)
//            partials: 16 slots, stride 32 floats | counter (int) — far above.
#define P_OFF   (2 * NPIX)
#define P_STRIDE 32
#define C_OFF   (P_OFF + 16 * P_STRIDE)

// ---------------------------------------------------------------------------
// Kernel 1: pack target into per-column bitmasks (transposed layout).
// Grid 64 x 512. Block = 32 columns of one image. Thread (h=tid>>8,
// j=(tid>>5)&7, c=tid&31) packs HALF a word (16 rows) with coalesced row
// reads; halves merged via LDS. 2x shorter serial load chain than round 3.
// Also zeroes the reduction partials + counter for kernel 2.
// ---------------------------------------------------------------------------
__global__ __launch_bounds__(512) void pack_masks_t(
    const float* __restrict__ tgt,
    float* __restrict__ ws) {
  __shared__ unsigned int halfw[2][8][32];

  if (blockIdx.x == 0) {
    if (threadIdx.x < 16) ws[P_OFF + threadIdx.x * P_STRIDE] = 0.0f;
    if (threadIdx.x == 16) ((int*)ws)[C_OFF] = 0;
  }

  int tid = threadIdx.x;
  int h = tid >> 8;           // half-word: rows 16h..16h+15
  int j = (tid >> 5) & 7;     // word id
  int c = tid & 31;           // col within tile
  int im = blockIdx.x >> 3;
  int w = ((blockIdx.x & 7) << 5) + c;
  size_t ib = (size_t)im * (HH * WW) + (size_t)(32 * j + 16 * h) * WW + w;

  unsigned int m = 0;
#pragma unroll
  for (int i = 0; i < 16; ++i) {
    float t = tgt[ib + (size_t)i * WW];
    m |= (t > 0.5f ? 1u : 0u) << i;
  }
  halfw[h][j][c] = m;
  __syncthreads();

  if (h == 0) {
    unsigned int full = halfw[0][j][c] | (halfw[1][j][c] << 16);
    ((unsigned int*)ws)[im * 2048 + w * 8 + j] = full;   // transposed
  }
}

// ---------------------------------------------------------------------------
// Kernel 2: vertical distances from bitmasks (verified clz/ctz + carry
// chains), then PER-LANE CENTER-OUT lower envelope: start at own group,
// expand +-1 group/iter, exit when all lanes' d2 <= (dist to nearest
// unscanned col)^2 — exact; capped at +-16 groups (>=64-col one-sided
// coverage, same guarantee as the verified round-3 window). Loss +
// two-level reduction unchanged from round 3.
// ---------------------------------------------------------------------------
#define ENV_G(gg) { float4 v = s4[gg];                            \
    float D0 = fw - (float)((gg) << 2);                           \
    d2 = fminf(d2, fmaf(D0, D0, v.x));                            \
    float D1 = D0 - 1.0f; d2 = fminf(d2, fmaf(D1, D1, v.y));      \
    float D2 = D0 - 2.0f; d2 = fminf(d2, fmaf(D2, D2, v.z));      \
    float D3 = D0 - 3.0f; d2 = fminf(d2, fmaf(D3, D3, v.w)); }

__global__ __launch_bounds__(1024) void edt_row_loss5(
    const float* __restrict__ pred,
    float* __restrict__ ws,
    float* __restrict__ out) {
  __shared__ __align__(16) float lA[4][WW];
  __shared__ __align__(16) float lB[4][WW];
  __shared__ float wsum[16];
  __shared__ int lastFlag;

  const unsigned int* maskws = (const unsigned int*)ws;
  float* partials = ws + P_OFF;
  int* counter = ((int*)ws) + C_OFF;

  int tid = threadIdx.x;
  int im = blockIdx.x >> 6;   // image
  int rg = blockIdx.x & 63;   // row-group (4 rows)
  int r = tid >> 8;           // row within group (wave-uniform)
  int w = tid & 255;          // column
  int R = 4 * rg + r;         // row in image
  int k = R >> 5;             // word id (wave-uniform)
  int rr = R & 31;            // bit within word

  // transposed mask load: 2 x uint4, fully coalesced (32 B/lane)
  const uint4* mp = (const uint4*)(maskws + im * 2048 + w * 8);
  uint4 mlo = mp[0], mhi = mp[1];
  unsigned int M[8] = {mlo.x, mlo.y, mlo.z, mlo.w, mhi.x, mhi.y, mhi.z, mhi.w};

  float x = pred[(size_t)blockIdx.x * (4 * WW) + tid];

  // cross-word carries (A = bg = ~fg, B = fg) — verified select chains
  int fcA = BIGBIG, fcB = BIGBIG, bcA = BIGBIG, bcB = BIGBIG;
  {
    int cA = BIGBIG, cB = BIGBIG;
#pragma unroll
    for (int j = 0; j < 8; ++j) {
      if (j == k) { fcA = cA; fcB = cB; }
      unsigned int a = ~M[j], bm = M[j];
      cA = a  ? (int)__builtin_clz(a)  : cA + 32;
      cB = bm ? (int)__builtin_clz(bm) : cB + 32;
    }
  }
  {
    int cA = BIGBIG, cB = BIGBIG;
#pragma unroll
    for (int j = 7; j >= 0; --j) {
      if (j == k) { bcA = cA; bcB = cB; }
      unsigned int a = ~M[j], bm = M[j];
      cA = a  ? (int)__builtin_ctz(a)  : cA + 32;
      cB = bm ? (int)__builtin_ctz(bm) : cB + 32;
    }
  }

  unsigned int mk = M[k];
  bool fg = (mk >> rr) & 1u;
  float t = fg ? 1.0f : 0.0f;

  // vertical distances for this pixel, both feature sets (verified)
  {
    unsigned int mA = ~mk;
    unsigned int xx = mA << (31 - rr);
    unsigned int yy = mA >> rr;
    int df = xx ? (int)__builtin_clz(xx) : (rr + 1 + fcA);
    int db = yy ? (int)__builtin_ctz(yy) : (32 - rr + bcA);
    int d = min(min(df, db), BIGI);
    lA[r][w] = (float)(d * d);
  }
  {
    unsigned int xx = mk << (31 - rr);
    unsigned int yy = mk >> rr;
    int df = xx ? (int)__builtin_clz(xx) : (rr + 1 + fcB);
    int db = yy ? (int)__builtin_ctz(yy) : (32 - rr + bcB);
    int d = min(min(df, db), BIGI);
    lB[r][w] = (float)(d * d);
  }
  __syncthreads();

  // per-lane center-out lower envelope with exact per-lane bound
  const float4* s4 = (const float4*)(fg ? lA[r] : lB[r]);
  int gc = w >> 2;            // own group (per-lane)
  float fw = (float)w;
  float d2 = 1e30f;

  ENV_G(gc);
  for (int dlt = 1; dlt <= 16; ++dlt) {
    int gl = gc - dlt, gr = gc + dlt;
    // nearest unscanned columns (before scanning ring dlt)
    int bl = (gl >= 0) ? (w - 4 * gl - 3) : 100000;
    int br = (gr <= 63) ? (4 * gr - w) : 100000;
    int bb = min(bl, br);
    float bb2 = (float)bb * (float)bb;
    if (__all(d2 <= bb2)) break;
    if (gl >= 0) ENV_G(gl);
    if (gr <= 63) ENV_G(gr);
  }

  float dd = sqrtf(d2);
  float weight = 1.0f / (1.0f + __expf((dd - 3.0f) * 0.2f));
  float bce = fmaxf(x, 0.0f) - x * t + log1pf(__expf(-fabsf(x)));
  float c = bce * weight * (1.0f / (float)NPIX);

  // two-level reduction (unchanged, verified round 3)
#pragma unroll
  for (int off = 32; off > 0; off >>= 1) c += __shfl_down(c, off, 64);
  if ((tid & 63) == 0) wsum[tid >> 6] = c;
  __syncthreads();

  if (tid < 64) {
    float v = (tid < 16) ? wsum[tid] : 0.0f;
#pragma unroll
    for (int off = 8; off > 0; off >>= 1) v += __shfl_down(v, off, 64);
    if (tid == 0) {
      atomicAdd(&partials[(blockIdx.x & 15) * P_STRIDE], v);
      __threadfence();
      int done = atomicAdd(counter, 1);
      lastFlag = (done == (int)gridDim.x - 1) ? 1 : 0;
    }
  }
  __syncthreads();

  if (lastFlag && tid < 64) {
    float v = (tid < 16) ? atomicAdd(&partials[tid * P_STRIDE], 0.0f) : 0.0f;
#pragma unroll
    for (int off = 8; off > 0; off >>= 1) v += __shfl_down(v, off, 64);
    if (tid == 0) out[0] = v;
  }
}

extern "C" void kernel_launch(void* const* d_in, const int* in_sizes, int n_in,
                              void* d_out, int out_size, void* d_ws, size_t ws_size,
                              hipStream_t stream) {
  const float* pred = (const float*)d_in[0];
  const float* tgt  = (const float*)d_in[1];
  float* out = (float*)d_out;
  float* ws  = (float*)d_ws;

  pack_masks_t<<<dim3(64), dim3(512), 0, stream>>>(tgt, ws);
  edt_row_loss5<<<dim3(512), dim3(1024), 0, stream>>>(pred, ws, out);
}

// Round 7
// 67.589 us; speedup vs baseline: 1.3202x; 1.0342x over previous
//
#include <hip/hip_runtime.h>
#include <math.h>

#define BB 8
#define HH 256
#define WW 256
#define NPIX (BB*HH*WW)   // 524288
#define BIGI 512          // H + W, the reference cap
#define BIGBIG (1<<20)

// ws layout: masks (u32) [0, 16384) = 64 KB, TRANSPOSED: mask[im][w][j]
//            (im=0..7 image, w=0..255 column, j=0..7 word of rows 32j..32j+31)
//            partials: 16 slots, stride 32 floats | counter (int) — far above.
#define P_OFF   (2 * NPIX)
#define P_STRIDE 32
#define C_OFF   (P_OFF + 16 * P_STRIDE)

// ---------------------------------------------------------------------------
// Kernel 1: pack target into per-column bitmasks (transposed layout).
// Grid 64 x 512. Block = 32 columns of one image. Thread (h=tid>>8,
// j=(tid>>5)&7, c=tid&31) packs HALF a word (16 rows) with coalesced row
// reads; halves merged via LDS. Also zeroes reduction partials + counter.
// (unchanged from round 6 — verified)
// ---------------------------------------------------------------------------
__global__ __launch_bounds__(512) void pack_masks_t(
    const float* __restrict__ tgt,
    float* __restrict__ ws) {
  __shared__ unsigned int halfw[2][8][32];

  if (blockIdx.x == 0) {
    if (threadIdx.x < 16) ws[P_OFF + threadIdx.x * P_STRIDE] = 0.0f;
    if (threadIdx.x == 16) ((int*)ws)[C_OFF] = 0;
  }

  int tid = threadIdx.x;
  int h = tid >> 8;           // half-word: rows 16h..16h+15
  int j = (tid >> 5) & 7;     // word id
  int c = tid & 31;           // col within tile
  int im = blockIdx.x >> 3;
  int w = ((blockIdx.x & 7) << 5) + c;
  size_t ib = (size_t)im * (HH * WW) + (size_t)(32 * j + 16 * h) * WW + w;

  unsigned int m = 0;
#pragma unroll
  for (int i = 0; i < 16; ++i) {
    float t = tgt[ib + (size_t)i * WW];
    m |= (t > 0.5f ? 1u : 0u) << i;
  }
  halfw[h][j][c] = m;
  __syncthreads();

  if (h == 0) {
    unsigned int full = halfw[0][j][c] | (halfw[1][j][c] << 16);
    ((unsigned int*)ws)[im * 2048 + w * 8 + j] = full;   // transposed
  }
}

// ---------------------------------------------------------------------------
// Kernel 2: TWO PIXELS PER THREAD (same column, rows R and R+4). Block owns
// 8 rows (grid 256 x 1024). Shares the 32-B mask load and the clz/ctz carry
// chains between both pixels (8 extra cndmask captures); halves block count
// -> reduction/launch overhead. Envelope: per-lane center-out with merged
// exact early exit over both pixels (verified bound, +-16 group cap).
// ---------------------------------------------------------------------------
__device__ __forceinline__ void env4(const float4* __restrict__ s4, int gg,
                                     float fw, float& d2) {
  float4 v = s4[gg];
  float D0 = fw - (float)(gg << 2);
  d2 = fminf(d2, fmaf(D0, D0, v.x));
  float D1 = D0 - 1.0f; d2 = fminf(d2, fmaf(D1, D1, v.y));
  float D2 = D0 - 2.0f; d2 = fminf(d2, fmaf(D2, D2, v.z));
  float D3 = D0 - 3.0f; d2 = fminf(d2, fmaf(D3, D3, v.w));
}

__global__ __launch_bounds__(1024) void edt_row_loss6(
    const float* __restrict__ pred,
    float* __restrict__ ws,
    float* __restrict__ out) {
  __shared__ __align__(16) float lA[8][WW];
  __shared__ __align__(16) float lB[8][WW];
  __shared__ float wsum[16];
  __shared__ int lastFlag;

  const unsigned int* maskws = (const unsigned int*)ws;
  float* partials = ws + P_OFF;
  int* counter = ((int*)ws) + C_OFF;

  int tid = threadIdx.x;
  int im = blockIdx.x >> 5;   // image
  int rg = blockIdx.x & 31;   // 8-row group
  int r = tid >> 8;           // row within group (wave-uniform, 0..3)
  int w = tid & 255;          // column
  int R0 = 8 * rg + r;        // pixel 0 row
  int R1 = R0 + 4;            // pixel 1 row
  int k0 = R0 >> 5, rr0 = R0 & 31;
  int k1 = R1 >> 5, rr1 = R1 & 31;

  // transposed mask load: 2 x uint4, fully coalesced (32 B/lane), shared
  const uint4* mp = (const uint4*)(maskws + im * 2048 + w * 8);
  uint4 mlo = mp[0], mhi = mp[1];
  unsigned int M[8] = {mlo.x, mlo.y, mlo.z, mlo.w, mhi.x, mhi.y, mhi.z, mhi.w};

  size_t pb = (size_t)blockIdx.x * 2048 + tid;
  float x0 = pred[pb];
  float x1 = pred[pb + 1024];

  // cross-word carries (A = bg = ~fg, B = fg), captured at BOTH k's
  int fc0A = BIGBIG, fc0B = BIGBIG, fc1A = BIGBIG, fc1B = BIGBIG;
  int bc0A = BIGBIG, bc0B = BIGBIG, bc1A = BIGBIG, bc1B = BIGBIG;
  {
    int cA = BIGBIG, cB = BIGBIG;
#pragma unroll
    for (int j = 0; j < 8; ++j) {
      if (j == k0) { fc0A = cA; fc0B = cB; }
      if (j == k1) { fc1A = cA; fc1B = cB; }
      unsigned int a = ~M[j], bm = M[j];
      cA = a  ? (int)__builtin_clz(a)  : cA + 32;
      cB = bm ? (int)__builtin_clz(bm) : cB + 32;
    }
  }
  {
    int cA = BIGBIG, cB = BIGBIG;
#pragma unroll
    for (int j = 7; j >= 0; --j) {
      if (j == k1) { bc1A = cA; bc1B = cB; }
      if (j == k0) { bc0A = cA; bc0B = cB; }
      unsigned int a = ~M[j], bm = M[j];
      cA = a  ? (int)__builtin_ctz(a)  : cA + 32;
      cB = bm ? (int)__builtin_ctz(bm) : cB + 32;
    }
  }

  unsigned int mk0 = M[k0], mk1 = M[k1];
  bool fg0 = (mk0 >> rr0) & 1u;
  bool fg1 = (mk1 >> rr1) & 1u;
  float t0 = fg0 ? 1.0f : 0.0f;
  float t1 = fg1 ? 1.0f : 0.0f;

  // vertical distances, both pixels, both feature sets (verified formulas)
  {
    unsigned int mA = ~mk0;
    unsigned int xx = mA << (31 - rr0), yy = mA >> rr0;
    int df = xx ? (int)__builtin_clz(xx) : (rr0 + 1 + fc0A);
    int db = yy ? (int)__builtin_ctz(yy) : (32 - rr0 + bc0A);
    int d = min(min(df, db), BIGI);
    lA[r][w] = (float)(d * d);
  }
  {
    unsigned int xx = mk0 << (31 - rr0), yy = mk0 >> rr0;
    int df = xx ? (int)__builtin_clz(xx) : (rr0 + 1 + fc0B);
    int db = yy ? (int)__builtin_ctz(yy) : (32 - rr0 + bc0B);
    int d = min(min(df, db), BIGI);
    lB[r][w] = (float)(d * d);
  }
  {
    unsigned int mA = ~mk1;
    unsigned int xx = mA << (31 - rr1), yy = mA >> rr1;
    int df = xx ? (int)__builtin_clz(xx) : (rr1 + 1 + fc1A);
    int db = yy ? (int)__builtin_ctz(yy) : (32 - rr1 + bc1A);
    int d = min(min(df, db), BIGI);
    lA[r + 4][w] = (float)(d * d);
  }
  {
    unsigned int xx = mk1 << (31 - rr1), yy = mk1 >> rr1;
    int df = xx ? (int)__builtin_clz(xx) : (rr1 + 1 + fc1B);
    int db = yy ? (int)__builtin_ctz(yy) : (32 - rr1 + bc1B);
    int d = min(min(df, db), BIGI);
    lB[r + 4][w] = (float)(d * d);
  }
  __syncthreads();

  // per-lane center-out lower envelope, merged over both pixels
  const float4* s40 = (const float4*)(fg0 ? lA[r] : lB[r]);
  const float4* s41 = (const float4*)(fg1 ? lA[r + 4] : lB[r + 4]);
  int gc = w >> 2;
  float fw = (float)w;
  float d2a = 1e30f, d2b = 1e30f;

  env4(s40, gc, fw, d2a);
  env4(s41, gc, fw, d2b);
  for (int dlt = 1; dlt <= 16; ++dlt) {
    int gl = gc - dlt, gr = gc + dlt;
    int bl = (gl >= 0) ? (w - 4 * gl - 3) : 100000;
    int br = (gr <= 63) ? (4 * gr - w) : 100000;
    int bb = min(bl, br);
    float bb2 = (float)bb * (float)bb;
    if (__all(d2a <= bb2 && d2b <= bb2)) break;
    if (gl >= 0) { env4(s40, gl, fw, d2a); env4(s41, gl, fw, d2b); }
    if (gr <= 63) { env4(s40, gr, fw, d2a); env4(s41, gr, fw, d2b); }
  }

  float dd0 = sqrtf(d2a);
  float wt0 = 1.0f / (1.0f + __expf((dd0 - 3.0f) * 0.2f));
  float bce0 = fmaxf(x0, 0.0f) - x0 * t0 + log1pf(__expf(-fabsf(x0)));
  float dd1 = sqrtf(d2b);
  float wt1 = 1.0f / (1.0f + __expf((dd1 - 3.0f) * 0.2f));
  float bce1 = fmaxf(x1, 0.0f) - x1 * t1 + log1pf(__expf(-fabsf(x1)));
  float c = (bce0 * wt0 + bce1 * wt1) * (1.0f / (float)NPIX);

  // two-level reduction (round-3-verified; counter vs gridDim.x)
#pragma unroll
  for (int off = 32; off > 0; off >>= 1) c += __shfl_down(c, off, 64);
  if ((tid & 63) == 0) wsum[tid >> 6] = c;
  __syncthreads();

  if (tid < 64) {
    float v = (tid < 16) ? wsum[tid] : 0.0f;
#pragma unroll
    for (int off = 8; off > 0; off >>= 1) v += __shfl_down(v, off, 64);
    if (tid == 0) {
      atomicAdd(&partials[(blockIdx.x & 15) * P_STRIDE], v);
      __threadfence();
      int done = atomicAdd(counter, 1);
      lastFlag = (done == (int)gridDim.x - 1) ? 1 : 0;
    }
  }
  __syncthreads();

  if (lastFlag && tid < 64) {
    float v = (tid < 16) ? atomicAdd(&partials[tid * P_STRIDE], 0.0f) : 0.0f;
#pragma unroll
    for (int off = 8; off > 0; off >>= 1) v += __shfl_down(v, off, 64);
    if (tid == 0) out[0] = v;
  }
}

extern "C" void kernel_launch(void* const* d_in, const int* in_sizes, int n_in,
                              void* d_out, int out_size, void* d_ws, size_t ws_size,
                              hipStream_t stream) {
  const float* pred = (const float*)d_in[0];
  const float* tgt  = (const float*)d_in[1];
  float* out = (float*)d_out;
  float* ws  = (float*)d_ws;

  pack_masks_t<<<dim3(64), dim3(512), 0, stream>>>(tgt, ws);
  edt_row_loss6<<<dim3(256), dim3(1024), 0, stream>>>(pred, ws, out);
}

// Round 8
// 67.072 us; speedup vs baseline: 1.3303x; 1.0077x over previous
//
#include <hip/hip_runtime.h>
#include <math.h>

#define BB 8
#define HH 256
#define WW 256
#define NPIX (BB*HH*WW)   // 524288
#define BIGI 512          // H + W, the reference cap
#define BIGBIG (1<<20)

// ws layout: masks (u32) [0, 16384) = 64 KB, TRANSPOSED: mask[im][w][j]
//            (im=0..7 image, w=0..255 column, j=0..7 word of rows 32j..32j+31)
//            partials: 16 slots, stride 32 floats | counter (int) — far above.
#define P_OFF   (2 * NPIX)
#define P_STRIDE 32
#define C_OFF   (P_OFF + 16 * P_STRIDE)

// ---------------------------------------------------------------------------
// Kernel 1: pack target into per-column bitmasks (transposed layout).
// Grid 128 x 512 (2x the CU coverage of round 6/7's 64-block version).
// Block = (image, 32-col tile, half-image v): rows 128v..128v+127.
// Thread (h=tid>>7 eighth-chunk, jl=(tid>>5)&3 word-in-half, c=tid&31):
// packs 8 rows of word j=4v+jl with coalesced row reads; 4 chunks merged
// via LDS. Also zeroes reduction partials + counter (verified pattern).
// ---------------------------------------------------------------------------
__global__ __launch_bounds__(512) void pack_masks_t2(
    const float* __restrict__ tgt,
    float* __restrict__ ws) {
  __shared__ unsigned int chunk[4][4][32];

  if (blockIdx.x == 0) {
    if (threadIdx.x < 16) ws[P_OFF + threadIdx.x * P_STRIDE] = 0.0f;
    if (threadIdx.x == 16) ((int*)ws)[C_OFF] = 0;
  }

  int tid = threadIdx.x;
  int c  = tid & 31;          // col within tile
  int jl = (tid >> 5) & 3;    // word within half
  int h  = tid >> 7;          // 8-row chunk within word (0..3)
  int im = blockIdx.x >> 4;   // image
  int tl = (blockIdx.x >> 1) & 7;  // 32-col tile
  int v  = blockIdx.x & 1;    // half-image (rows 128v..)
  int j  = 4 * v + jl;        // global word id
  int w  = (tl << 5) + c;     // column
  size_t ib = (size_t)im * (HH * WW) + (size_t)(32 * j + 8 * h) * WW + w;

  unsigned int m = 0;
#pragma unroll
  for (int i = 0; i < 8; ++i) {
    float t = tgt[ib + (size_t)i * WW];
    m |= (t > 0.5f ? 1u : 0u) << i;
  }
  chunk[h][jl][c] = m;
  __syncthreads();

  if (h == 0) {
    unsigned int full = chunk[0][jl][c] | (chunk[1][jl][c] << 8) |
                        (chunk[2][jl][c] << 16) | (chunk[3][jl][c] << 24);
    ((unsigned int*)ws)[im * 2048 + w * 8 + j] = full;   // transposed
  }
}

// ---------------------------------------------------------------------------
// Kernel 2: FOUR PIXELS PER THREAD (same column, rows 8rg+4r+p, p=0..3).
// Grid 256 x 512 (1 block/CU, all CUs covered; waves halved vs round 7).
// Shares the 32-B mask load and the clz/ctz carry chains across 4 pixels.
// Envelope: per-lane center-out with merged exact early exit over all 4
// pixels (same verified bound, +-16 group cap). Loss + two-level reduction
// = round-3-verified scheme (counter vs gridDim.x).
// ---------------------------------------------------------------------------
__device__ __forceinline__ void env4(const float4* __restrict__ s4, int gg,
                                     float fw, float& d2) {
  float4 v = s4[gg];
  float D0 = fw - (float)(gg << 2);
  d2 = fminf(d2, fmaf(D0, D0, v.x));
  float D1 = D0 - 1.0f; d2 = fminf(d2, fmaf(D1, D1, v.y));
  float D2 = D0 - 2.0f; d2 = fminf(d2, fmaf(D2, D2, v.z));
  float D3 = D0 - 3.0f; d2 = fminf(d2, fmaf(D3, D3, v.w));
}

__global__ __launch_bounds__(512) void edt_row_loss7(
    const float* __restrict__ pred,
    float* __restrict__ ws,
    float* __restrict__ out) {
  __shared__ __align__(16) float lA[8][WW];
  __shared__ __align__(16) float lB[8][WW];
  __shared__ float wsum[8];
  __shared__ int lastFlag;

  const unsigned int* maskws = (const unsigned int*)ws;
  float* partials = ws + P_OFF;
  int* counter = ((int*)ws) + C_OFF;

  int tid = threadIdx.x;
  int bid = blockIdx.x;
  int im = bid >> 5;          // image
  int rg = bid & 31;          // 8-row group
  int r = tid >> 8;           // half (wave-uniform, 0..1): rows 4r..4r+3
  int w = tid & 255;          // column
  int R0 = 8 * rg + 4 * r;    // first of this thread's 4 rows

  int kq[4], rq[4];
#pragma unroll
  for (int p = 0; p < 4; ++p) { kq[p] = (R0 + p) >> 5; rq[p] = (R0 + p) & 31; }

  // transposed mask load: 2 x uint4, fully coalesced (32 B/lane), shared x4
  const uint4* mp = (const uint4*)(maskws + im * 2048 + w * 8);
  uint4 mlo = mp[0], mhi = mp[1];
  unsigned int M[8] = {mlo.x, mlo.y, mlo.z, mlo.w, mhi.x, mhi.y, mhi.z, mhi.w};

  size_t pb = (size_t)bid * 2048 + (size_t)r * 1024 + w;
  float x[4];
#pragma unroll
  for (int p = 0; p < 4; ++p) x[p] = pred[pb + (size_t)(p << 8)];

  // cross-word carries (A = bg = ~fg, B = fg), captured at all 4 k's
  int fcA[4], fcB[4], bcA[4], bcB[4];
  {
    int cA = BIGBIG, cB = BIGBIG;
#pragma unroll
    for (int j = 0; j < 8; ++j) {
#pragma unroll
      for (int p = 0; p < 4; ++p)
        if (j == kq[p]) { fcA[p] = cA; fcB[p] = cB; }
      unsigned int a = ~M[j], bm = M[j];
      cA = a  ? (int)__builtin_clz(a)  : cA + 32;
      cB = bm ? (int)__builtin_clz(bm) : cB + 32;
    }
  }
  {
    int cA = BIGBIG, cB = BIGBIG;
#pragma unroll
    for (int j = 7; j >= 0; --j) {
#pragma unroll
      for (int p = 0; p < 4; ++p)
        if (j == kq[p]) { bcA[p] = cA; bcB[p] = cB; }
      unsigned int a = ~M[j], bm = M[j];
      cA = a  ? (int)__builtin_ctz(a)  : cA + 32;
      cB = bm ? (int)__builtin_ctz(bm) : cB + 32;
    }
  }

  bool fg[4]; float t[4];
#pragma unroll
  for (int p = 0; p < 4; ++p) {
    unsigned int mk = M[kq[p]];
    int rr = rq[p];
    fg[p] = (mk >> rr) & 1u;
    t[p] = fg[p] ? 1.0f : 0.0f;
    // vertical distances (verified clz/ctz formulas), both feature sets
    {
      unsigned int mA = ~mk;
      unsigned int xx = mA << (31 - rr), yy = mA >> rr;
      int df = xx ? (int)__builtin_clz(xx) : (rr + 1 + fcA[p]);
      int db = yy ? (int)__builtin_ctz(yy) : (32 - rr + bcA[p]);
      int d = min(min(df, db), BIGI);
      lA[(r << 2) + p][w] = (float)(d * d);
    }
    {
      unsigned int xx = mk << (31 - rr), yy = mk >> rr;
      int df = xx ? (int)__builtin_clz(xx) : (rr + 1 + fcB[p]);
      int db = yy ? (int)__builtin_ctz(yy) : (32 - rr + bcB[p]);
      int d = min(min(df, db), BIGI);
      lB[(r << 2) + p][w] = (float)(d * d);
    }
  }
  __syncthreads();

  // per-lane center-out lower envelope, merged exact exit over 4 pixels
  const float4* s4[4];
  float d2[4] = {1e30f, 1e30f, 1e30f, 1e30f};
#pragma unroll
  for (int p = 0; p < 4; ++p)
    s4[p] = (const float4*)(fg[p] ? lA[(r << 2) + p] : lB[(r << 2) + p]);

  int gc = w >> 2;
  float fw = (float)w;
#pragma unroll
  for (int p = 0; p < 4; ++p) env4(s4[p], gc, fw, d2[p]);

  for (int dlt = 1; dlt <= 16; ++dlt) {
    int gl = gc - dlt, gr = gc + dlt;
    int bl = (gl >= 0) ? (w - 4 * gl - 3) : 100000;
    int br = (gr <= 63) ? (4 * gr - w) : 100000;
    int bb = min(bl, br);
    float bb2 = (float)bb * (float)bb;
    if (__all(d2[0] <= bb2 && d2[1] <= bb2 && d2[2] <= bb2 && d2[3] <= bb2))
      break;
    if (gl >= 0) {
#pragma unroll
      for (int p = 0; p < 4; ++p) env4(s4[p], gl, fw, d2[p]);
    }
    if (gr <= 63) {
#pragma unroll
      for (int p = 0; p < 4; ++p) env4(s4[p], gr, fw, d2[p]);
    }
  }

  float c = 0.0f;
#pragma unroll
  for (int p = 0; p < 4; ++p) {
    float dd = sqrtf(d2[p]);
    float wt = 1.0f / (1.0f + __expf((dd - 3.0f) * 0.2f));
    float bce = fmaxf(x[p], 0.0f) - x[p] * t[p] + log1pf(__expf(-fabsf(x[p])));
    c += bce * wt;
  }
  c *= (1.0f / (float)NPIX);

  // two-level reduction (round-3-verified; counter vs gridDim.x)
#pragma unroll
  for (int off = 32; off > 0; off >>= 1) c += __shfl_down(c, off, 64);
  if ((tid & 63) == 0) wsum[tid >> 6] = c;
  __syncthreads();

  if (tid < 64) {
    float v = (tid < 8) ? wsum[tid] : 0.0f;
#pragma unroll
    for (int off = 4; off > 0; off >>= 1) v += __shfl_down(v, off, 64);
    if (tid == 0) {
      atomicAdd(&partials[(bid & 15) * P_STRIDE], v);
      __threadfence();
      int done = atomicAdd(counter, 1);
      lastFlag = (done == (int)gridDim.x - 1) ? 1 : 0;
    }
  }
  __syncthreads();

  if (lastFlag && tid < 64) {
    float v = (tid < 16) ? atomicAdd(&partials[tid * P_STRIDE], 0.0f) : 0.0f;
#pragma unroll
    for (int off = 8; off > 0; off >>= 1) v += __shfl_down(v, off, 64);
    if (tid == 0) out[0] = v;
  }
}

extern "C" void kernel_launch(void* const* d_in, const int* in_sizes, int n_in,
                              void* d_out, int out_size, void* d_ws, size_t ws_size,
                              hipStream_t stream) {
  const float* pred = (const float*)d_in[0];
  const float* tgt  = (const float*)d_in[1];
  float* out = (float*)d_out;
  float* ws  = (float*)d_ws;

  pack_masks_t2<<<dim3(128), dim3(512), 0, stream>>>(tgt, ws);
  edt_row_loss7<<<dim3(256), dim3(512), 0, stream>>>(pred, ws, out);
}